// Round 1
// 190.947 us; speedup vs baseline: 1.0956x; 1.0956x over previous
//
#include <hip/hip_runtime.h>
#include <math.h>

// q,k,v: [B=2, H=16, N=2048, Dh=64] fp32.  BH = 32 independent heads.
#define BH 32
#define NN 2048
#define DD 64
#define BHNN (BH * NN)        // 65536 rows total
#define QK ((size_t)BH * NN * DD)  // 4,194,304 elems per tensor
#define LDK 72                // padded LDS row (fp16): stride 144B, conflict-free (measured 0)

// 8 * log2(e): logits produced in base-2 domain so all softmax exps are a bare
// v_exp_f32 (exp2). Softmax is invariant to the base change.
#define QSCALE 11.5415603f

// Precision scheme (R11): fp16 q-hi/lo x fp16 k-single, 2 MFMAs per k-slice.
// fp16 products are exact in the fp32 MFMA accumulator (11x11 bits < 24);
// q captured to ~2^-22 by hi/lo; only k's single-fp16 rounding remains:
// per-logit sigma ~0.026 base-2 -> output perturbation <~0.05, vs the bf16
// (hi,lo)x3-MFMA scheme this is 2/3 MFMA work and 1/2 LDS traffic.
typedef __attribute__((ext_vector_type(8)))  _Float16 halfx8;
typedef __attribute__((ext_vector_type(4)))  _Float16 halfx4;
typedef __attribute__((ext_vector_type(16))) float    floatx16;

__device__ inline float fexp2(float x) { return __builtin_amdgcn_exp2f(x); }

// C/D row for accumulator register r (0..15) given half = lane>>5 (verified R2).
__device__ inline int rowmap(int r, int half) {
    return (r & 3) + 8 * (r >> 2) + 4 * half;
}

// ---------------------------------------------------------------------------
// Pre-convert: q -> fp16 hi/lo (QSCALE folded), k -> fp16 single.
// ---------------------------------------------------------------------------
__global__ __launch_bounds__(256) void convert_kernel(const float4* __restrict__ q,
                                                      const float4* __restrict__ k,
                                                      _Float16* __restrict__ qhi,
                                                      _Float16* __restrict__ qlo,
                                                      _Float16* __restrict__ khi) {
    size_t gid = (size_t)blockIdx.x * 256 + threadIdx.x;  // float4 index, QK/4 total
    float4 qa = q[gid];
    float4 ka = k[gid];
    float qf[4] = {qa.x, qa.y, qa.z, qa.w};
    float kf[4] = {ka.x, ka.y, ka.z, ka.w};
    halfx4 h, l, kh;
#pragma unroll
    for (int i = 0; i < 4; ++i) {
        float f = qf[i] * QSCALE;
        _Float16 hh = (_Float16)f;           // RN
        h[i] = hh;
        l[i] = (_Float16)(f - (float)hh);    // residual, RN
        kh[i] = (_Float16)kf[i];
    }
    *(halfx4*)&qhi[gid * 4] = h;
    *(halfx4*)&qlo[gid * 4] = l;
    *(halfx4*)&khi[gid * 4] = kh;
}

// ---- tile staging: 128 rows x 64 cols fp16, 16B chunks per thread ----------
__device__ inline void load_tile(const _Float16* __restrict__ khi_t,
                                 int tid, halfx8 rh[4]) {
#pragma unroll
    for (int i = 0; i < 4; ++i) {
        int c = tid + 256 * i;       // chunk 0..1023
        int r = c >> 3, s = c & 7;   // row, 16B slot
        rh[i] = *(const halfx8*)&khi_t[(size_t)r * 64 + s * 8];
    }
}
__device__ inline void write_tile(_Float16* Khi, int tid, const halfx8 rh[4]) {
#pragma unroll
    for (int i = 0; i < 4; ++i) {
        int c = tid + 256 * i;
        int r = c >> 3, s = c & 7;
        *(halfx8*)&Khi[r * LDK + s * 8] = rh[i];
    }
}

// ---- A-operand fragments: lane holds A[m=lane&31][k=(lane>>5)*8+j] ----------
__device__ inline void load_a(const _Float16* __restrict__ qhi_row,
                              const _Float16* __restrict__ qlo_row,
                              int half, halfx8 ah[4], halfx8 al[4]) {
#pragma unroll
    for (int ks = 0; ks < 4; ++ks) {
        ah[ks] = *(const halfx8*)&qhi_row[ks * 16 + half * 8];
        al[ks] = *(const halfx8*)&qlo_row[ks * 16 + half * 8];
    }
}

// ---------------------------------------------------------------------------
// Phase 1: per-row softmax stats (base-2), PARTIAL over an m-half.
// 1D grid 1024: idx = (bh + 32*ms) + 64*nblk -> blocks sharing a K-half are
// congruent mod 8 => same XCD (L2 locality). Lazy per-lane online stats.
// (256,2) is a floor, not a cap: with the fp16 scheme (~150-170 total regs,
// 18.4KB LDS) occupancy can float to 3 waves/SIMD naturally. The measured
// (256,3) spill wall (R5-R10) was for the 3-MFMA bf16 scheme; do not force 3.
// ---------------------------------------------------------------------------
__global__ __launch_bounds__(256, 2) void stats_kernel(const _Float16* __restrict__ qhi,
                                                       const _Float16* __restrict__ qlo,
                                                       const _Float16* __restrict__ khi,
                                                       float* __restrict__ smax_p,
                                                       float* __restrict__ sden_p) {
    __shared__ _Float16 Khi[128 * LDK];
    const int g    = blockIdx.x & 63;      // bh + 32*ms
    const int bh   = g & 31;
    const int ms   = g >> 5;               // m-split: tiles [ms*8, ms*8+8)
    const int n0   = (blockIdx.x >> 6) * 128;
    const int tid  = threadIdx.x;
    const int wave = tid >> 6, lane = tid & 63;
    const int half = lane >> 5, l31 = lane & 31;
    const size_t base = (size_t)bh * NN * DD;

    // A fragments: fixed rows for the whole kernel.
    halfx8 ah[4], al[4];
    {
        size_t ro = base + (size_t)(n0 + wave * 32 + l31) * DD;
        load_a(qhi + ro, qlo + ro, half, ah, al);
    }

    float m_run[16], d_run[16];
#pragma unroll
    for (int r = 0; r < 16; ++r) { m_run[r] = -INFINITY; d_run[r] = 0.f; }

    const _Float16* khi_b = khi + base;
    halfx8 rh[4];
    load_tile(khi_b + (size_t)(ms * 8) * 8192, tid, rh);

    for (int mti = 0; mti < 8; ++mti) {
        __syncthreads();                       // LDS consumers of prev tile done
        write_tile(Khi, tid, rh);
        __syncthreads();
        if (mti < 7) {                         // prefetch next tile under compute
            size_t toff = (size_t)(ms * 8 + mti + 1) * 8192;
            load_tile(khi_b + toff, tid, rh);
        }

        floatx16 acc[4];
#pragma unroll
        for (int t = 0; t < 4; ++t)
#pragma unroll
            for (int e = 0; e < 16; ++e) acc[t][e] = 0.f;

#pragma unroll
        for (int t = 0; t < 4; ++t) {
            const int mr = t * 32 + l31;
#pragma unroll
            for (int ks = 0; ks < 4; ++ks) {
                halfx8 bhf = *(const halfx8*)&Khi[mr * LDK + ks * 16 + half * 8];
                acc[t] = __builtin_amdgcn_mfma_f32_32x32x16_f16(ah[ks], bhf, acc[t], 0, 0, 0);
                acc[t] = __builtin_amdgcn_mfma_f32_32x32x16_f16(al[ks], bhf, acc[t], 0, 0, 0);
            }
        }

        // Lazy per-lane online stats, base-2 domain.
#pragma unroll
        for (int r = 0; r < 16; ++r) {
            float tmax = fmaxf(fmaxf(acc[0][r], acc[1][r]), fmaxf(acc[2][r], acc[3][r]));
            float m_new = fmaxf(m_run[r], tmax);
            float s = fexp2(acc[0][r] - m_new) + fexp2(acc[1][r] - m_new)
                    + fexp2(acc[2][r] - m_new) + fexp2(acc[3][r] - m_new);
            d_run[r] = d_run[r] * fexp2(m_run[r] - m_new) + s;
            m_run[r] = m_new;
        }
    }

    // Cross-lane combine within each 32-lane half (rows differ across halves).
    float* smp = smax_p + ((size_t)ms * BH + bh) * NN;
    float* sdp = sden_p + ((size_t)ms * BH + bh) * NN;
#pragma unroll
    for (int r = 0; r < 16; ++r) {
        float M = m_run[r];
#pragma unroll
        for (int off = 1; off < 32; off <<= 1)
            M = fmaxf(M, __shfl_xor(M, off));
        float dd = d_run[r] * fexp2(m_run[r] - M);
#pragma unroll
        for (int off = 1; off < 32; off <<= 1)
            dd += __shfl_xor(dd, off);
        if (l31 == 0) {
            int row = n0 + wave * 32 + rowmap(r, half);
            smp[row] = M;
            sdp[row] = dd;
        }
    }
}

// ---------------------------------------------------------------------------
// Combine the two m-split partials (base-2): M=max, den combined; store 1/den.
// ---------------------------------------------------------------------------
__global__ __launch_bounds__(256) void combine_kernel(const float* __restrict__ smax_p,
                                                      const float* __restrict__ sden_p,
                                                      float* __restrict__ smaxC,
                                                      float* __restrict__ sinvC) {
    int idx = blockIdx.x * 256 + threadIdx.x;  // BHNN total
    float m0 = smax_p[idx], m1 = smax_p[BHNN + idx];
    float d0 = sden_p[idx], d1 = sden_p[BHNN + idx];
    float M = fmaxf(m0, m1);
    float den = d0 * fexp2(m0 - M) + d1 * fexp2(m1 - M);
    smaxC[idx] = M;
    sinvC[idx] = 1.0f / den;
}

// ---------------------------------------------------------------------------
// Phase 2: partial w[m] over an n-half. 1D grid 1024 with mod-8 XCD swizzle.
// Block owns 128 cols (K tile staged once); waves stride 32-row strips.
// Per-row (M,1/den) staged in LDS once. fp16 scheme: 2 MFMAs + 1 LDS read
// per (t,ks); K tile is a single 18.4KB array.
// ---------------------------------------------------------------------------
__global__ __launch_bounds__(256, 2) void wsum_kernel(const _Float16* __restrict__ qhi,
                                                      const _Float16* __restrict__ qlo,
                                                      const _Float16* __restrict__ khi,
                                                      const float* __restrict__ smaxC,
                                                      const float* __restrict__ sinvC,
                                                      float* __restrict__ wpart) {
    __shared__ _Float16 Khi[128 * LDK];
    __shared__ float wred[4 * 128];
    __shared__ float Ms[1024];
    __shared__ float Is[1024];
    const int g    = blockIdx.x & 63;      // bh + 32*nz
    const int bh   = g & 31;
    const int nz   = g >> 5;               // n-split: rows [nz*1024, +1024)
    const int m0   = (blockIdx.x >> 6) * 128;
    const int tid  = threadIdx.x;
    const int wave = tid >> 6, lane = tid & 63;
    const int half = lane >> 5, l31 = lane & 31;
    const size_t base = (size_t)bh * NN * DD;

    {   // stage this block's K tile + row stats once
        halfx8 rh[4];
        load_tile(khi + base + (size_t)m0 * 64, tid, rh);
        write_tile(Khi, tid, rh);
        const float4* sm4 = (const float4*)(smaxC + (size_t)bh * NN + nz * 1024);
        const float4* si4 = (const float4*)(sinvC + (size_t)bh * NN + nz * 1024);
        *(float4*)&Ms[tid * 4] = sm4[tid];
        *(float4*)&Is[tid * 4] = si4[tid];
    }
    __syncthreads();

    float wacc[4] = {0.f, 0.f, 0.f, 0.f};

#pragma unroll
    for (int it = 0; it < 8; ++it) {
        const int ls = wave + it * 4;      // local strip 0..31
        halfx8 ah[4], al[4];
        {
            size_t ro = base + (size_t)((nz * 32 + ls) * 32 + l31) * DD;
            load_a(qhi + ro, qlo + ro, half, ah, al);
        }

        floatx16 acc[4];
#pragma unroll
        for (int t = 0; t < 4; ++t)
#pragma unroll
            for (int e = 0; e < 16; ++e) acc[t][e] = 0.f;

#pragma unroll
        for (int t = 0; t < 4; ++t) {
            const int mr = t * 32 + l31;
#pragma unroll
            for (int ks = 0; ks < 4; ++ks) {
                halfx8 bhf = *(const halfx8*)&Khi[mr * LDK + ks * 16 + half * 8];
                acc[t] = __builtin_amdgcn_mfma_f32_32x32x16_f16(ah[ks], bhf, acc[t], 0, 0, 0);
                acc[t] = __builtin_amdgcn_mfma_f32_32x32x16_f16(al[ks], bhf, acc[t], 0, 0, 0);
            }
        }

#pragma unroll
        for (int r = 0; r < 16; ++r) {
            const int lrow = ls * 32 + rowmap(r, half);   // broadcast LDS read
            float M   = Ms[lrow];
            float inv = Is[lrow];
#pragma unroll
            for (int t = 0; t < 4; ++t)
                wacc[t] += fexp2(acc[t][r] - M) * inv;
        }
    }

    // halves hold same cols, different rows: sum across halves, then waves.
#pragma unroll
    for (int t = 0; t < 4; ++t) wacc[t] += __shfl_xor(wacc[t], 32);
    if (half == 0) {
#pragma unroll
        for (int t = 0; t < 4; ++t) wred[wave * 128 + t * 32 + l31] = wacc[t];
    }
    __syncthreads();
    if (tid < 128) {
        float s = wred[tid] + wred[128 + tid] + wred[256 + tid] + wred[384 + tid];
        wpart[((size_t)nz * BH + bh) * NN + m0 + tid] = s;
    }
}

// ---------------------------------------------------------------------------
// Phase 3: out[b,h,m,d] = (w0[m]+w1[m]) * v[b,h,m,d]
// ---------------------------------------------------------------------------
__global__ __launch_bounds__(256) void out_kernel(const float* __restrict__ v,
                                                  const float* __restrict__ w0,
                                                  const float* __restrict__ w1,
                                                  float* __restrict__ out) {
    size_t gid = (size_t)blockIdx.x * 256 + threadIdx.x;  // float4 index
    const float4* v4 = (const float4*)v;
    float4* o4 = (float4*)out;
    float4 vv = v4[gid];
    float ww = w0[gid >> 4] + w1[gid >> 4];
    o4[gid] = make_float4(vv.x * ww, vv.y * ww, vv.z * ww, vv.w * ww);
}

extern "C" void kernel_launch(void* const* d_in, const int* in_sizes, int n_in,
                              void* d_out, int out_size, void* d_ws, size_t ws_size,
                              hipStream_t stream) {
    const float* q = (const float*)d_in[0];
    const float* k = (const float*)d_in[1];
    const float* v = (const float*)d_in[2];
    float* out = (float*)d_out;

    // Workspace (~27.2 MB), all fully rewritten each launch:
    _Float16* qhi = (_Float16*)d_ws;
    _Float16* qlo = qhi + QK;
    _Float16* khi = qlo + QK;
    float* smax_p = (float*)(khi + QK);       // 2*BHNN
    float* sden_p = smax_p + 2 * BHNN;        // 2*BHNN
    float* smaxC  = sden_p + 2 * BHNN;        // BHNN
    float* sinvC  = smaxC + BHNN;             // BHNN
    float* wpart  = sinvC + BHNN;             // 2*BHNN

    convert_kernel<<<QK / 4 / 256, 256, 0, stream>>>((const float4*)q, (const float4*)k,
                                                     qhi, qlo, khi);
    stats_kernel<<<1024, 256, 0, stream>>>(qhi, qlo, khi, smax_p, sden_p);
    combine_kernel<<<BHNN / 256, 256, 0, stream>>>(smax_p, sden_p, smaxC, sinvC);
    wsum_kernel<<<1024, 256, 0, stream>>>(qhi, qlo, khi, smaxC, sinvC, wpart);
    out_kernel<<<(BH * NN * DD / 4) / 256, 256, 0, stream>>>(v, wpart, wpart + BHNN, out);
}